// Round 1
// baseline (832.521 us; speedup 1.0000x reference)
//
#include <hip/hip_runtime.h>

#define NN 20000
#define NE 320000
#define CC 128
#define SS 10

__device__ __forceinline__ float silu_f(float x) { return x / (1.f + __expf(-x)); }

// ---------------- h = node_feats @ W_up, 8 nodes per 128-thread block ----------------
__global__ __launch_bounds__(128) void k_node_h(const float* __restrict__ nf,
                                                const float* __restrict__ W,
                                                float* __restrict__ h) {
  __shared__ __align__(16) float rows[8][CC];
  const int c = threadIdx.x;
  const int n0 = blockIdx.x * 8;
#pragma unroll
  for (int q = 0; q < 8; ++q) rows[q][c] = nf[(n0 + q) * CC + c];
  __syncthreads();
  float acc[8] = {0.f, 0.f, 0.f, 0.f, 0.f, 0.f, 0.f, 0.f};
  for (int k = 0; k < CC; k += 4) {
    const float w0 = W[(k + 0) * CC + c];
    const float w1 = W[(k + 1) * CC + c];
    const float w2 = W[(k + 2) * CC + c];
    const float w3 = W[(k + 3) * CC + c];
#pragma unroll
    for (int q = 0; q < 8; ++q) {
      float4 v = *(const float4*)&rows[q][k];
      acc[q] += v.x * w0 + v.y * w1 + v.z * w2 + v.w * w3;
    }
  }
#pragma unroll
  for (int q = 0; q < 8; ++q) h[(n0 + q) * CC + c] = acc[q];
}

// ---------------- CSR build: histogram / scan / fill ----------------
__global__ void k_hist(const int* __restrict__ recv, int* __restrict__ cnt) {
  int i = blockIdx.x * blockDim.x + threadIdx.x;
  if (i < NE) atomicAdd(&cnt[recv[i]], 1);
}

__global__ __launch_bounds__(1024) void k_scan(const int* __restrict__ cnt,
                                               int* __restrict__ offs,
                                               int* __restrict__ cur) {
  __shared__ int buf[1024];
  __shared__ int carry_s;
  const int t = threadIdx.x;
  if (t == 0) carry_s = 0;
  __syncthreads();
  for (int base = 0; base < NN; base += 1024) {
    int carry = carry_s;
    int v = (base + t < NN) ? cnt[base + t] : 0;
    int x = v;
    buf[t] = x;
    __syncthreads();
    for (int off = 1; off < 1024; off <<= 1) {
      int y = (t >= off) ? buf[t - off] : 0;
      __syncthreads();
      x += y;
      buf[t] = x;
      __syncthreads();
    }
    if (base + t < NN) {
      offs[base + t] = carry + x - v;
      cur[base + t] = carry + x - v;
    }
    __syncthreads();
    if (t == 1023) carry_s = carry + buf[1023];
    __syncthreads();
  }
  if (t == 0) offs[NN] = carry_s;
}

__global__ void k_fill(const int* __restrict__ recv, int* __restrict__ cur,
                       int* __restrict__ ord) {
  int i = blockIdx.x * blockDim.x + threadIdx.x;
  if (i < NE) {
    int r = recv[i];
    int pos = atomicAdd(&cur[r], 1);
    ord[pos] = i;
  }
}

// ---------------- edge aggregation: one node at a time per 256-thread block ----------------
// thread t: channel c = t&127, k-half p = t>>7 ; radial W2 half held in registers.
__global__ __launch_bounds__(256) void k_edge(
    const float* __restrict__ vectors, const float* __restrict__ lengths,
    const float* __restrict__ efeat, const int* __restrict__ senders,
    const float* __restrict__ hbuf, const float* __restrict__ W1,
    const float* __restrict__ B1, const float* __restrict__ W2,
    const int* __restrict__ offs, const int* __restrict__ ord,
    float* __restrict__ sout) {
  __shared__ float W1s[9 * 64];
  __shared__ float B1s[64];
  __shared__ float ed[12];
  __shared__ __align__(16) float hid[64];
  __shared__ float y1s[3];
  __shared__ float ps[4][256];
  const int t = threadIdx.x;
  const int c = t & 127, p = t >> 7;
  for (int i = t; i < 576; i += 256) W1s[i] = W1[i];
  if (t < 64) B1s[t] = B1[t];
  float w2a[32], w2b[32];
#pragma unroll
  for (int j = 0; j < 32; ++j) {
    int row = p * 32 + j;
    w2a[j] = W2[row * 256 + c];
    w2b[j] = W2[row * 256 + 128 + c];
  }
  __syncthreads();
  for (int n = blockIdx.x; n < NN; n += gridDim.x) {
    const int beg = offs[n], end = offs[n + 1];
    float s0 = 0.f, sx = 0.f, sy = 0.f, sz = 0.f;
    for (int ei = beg; ei < end; ++ei) {
      const int e = ord[ei];
      __syncthreads();  // protect ed/hid/y1s reuse from previous edge
      if (t < 3)
        ed[t] = vectors[e * 3 + t];
      else if (t == 3)
        ed[3] = lengths[e];
      else if (t < 12)
        ed[t] = efeat[e * 8 + (t - 4)];
      __syncthreads();
      if (t < 64) {
        float x = B1s[t];
#pragma unroll
        for (int k = 0; k < 8; ++k) x += ed[4 + k] * W1s[k * 64 + t];
        x += ed[3] * W1s[8 * 64 + t];
        hid[t] = silu_f(x);
      } else if (t < 67) {
        int i = t - 64;
        float nrm = sqrtf(ed[0] * ed[0] + ed[1] * ed[1] + ed[2] * ed[2]) + 1e-9f;
        y1s[i] = 1.7320508075688772f * ed[i] / nrm;
      }
      __syncthreads();
      const float hc = hbuf[senders[e] * CC + c];
      float w0 = 0.f, w1 = 0.f;
      const float4* h4 = (const float4*)&hid[p * 32];
#pragma unroll
      for (int j = 0; j < 8; ++j) {
        float4 hv = h4[j];
        w0 += hv.x * w2a[4 * j] + hv.y * w2a[4 * j + 1] + hv.z * w2a[4 * j + 2] +
              hv.w * w2a[4 * j + 3];
        w1 += hv.x * w2b[4 * j] + hv.y * w2b[4 * j + 1] + hv.z * w2b[4 * j + 2] +
              hv.w * w2b[4 * j + 3];
      }
      const float m = w1 * hc;
      s0 += w0 * hc;
      sx += m * y1s[0];
      sy += m * y1s[1];
      sz += m * y1s[2];
    }
    ps[0][t] = s0;
    ps[1][t] = sx;
    ps[2][t] = sy;
    ps[3][t] = sz;
    __syncthreads();
    const float inv = 1.f / 16.f;
    for (int idx = t; idx < 512; idx += 256) {
      int comp = idx >> 7, c2 = idx & 127;
      sout[(size_t)n * 512 + idx] = (ps[comp][c2] + ps[comp][128 + c2]) * inv;
    }
    __syncthreads();
  }
}

// ---------------- fused downstream: 8 nodes per 256-thread block ----------------
__global__ __launch_bounds__(256) void k_down(
    const float* __restrict__ sbuf, const float* __restrict__ attrs,
    const float* __restrict__ Wd0, const float* __restrict__ Wd1,
    const float* __restrict__ Wprod0, const float* __restrict__ Wprod1,
    const float* __restrict__ Wp0, const float* __restrict__ Wp1,
    const float* __restrict__ Wr1, const float* __restrict__ Wr2,
    const float* __restrict__ Wg, const float* __restrict__ wv,
    float* __restrict__ out_scalars, float* __restrict__ out_vec,
    float* __restrict__ out_nf) {
  __shared__ __align__(16) float X[8][4][CC];  // s, then b
  __shared__ __align__(16) float Y[8][4][CC];  // a, then h
  __shared__ float at_s[8][SS];
  __shared__ float mh_s[8][16];
  __shared__ float gate_s[8];
  const int t = threadIdx.x;
  const int c = t & 127, p = t >> 7;
  const int n0 = blockIdx.x * 8;
  float* Xf = &X[0][0][0];
  float* Yf = &Y[0][0][0];
  for (int i = t; i < 4096; i += 256) Xf[i] = sbuf[(size_t)n0 * 512 + i];
  for (int i = t; i < 8 * SS; i += 256) at_s[i / SS][i % SS] = attrs[n0 * SS + i];
  __syncthreads();
  // ---- stage A: a = s @ [Wd0 | Wd1] ----
  {
    float acc[4][4];
#pragma unroll
    for (int q = 0; q < 4; ++q)
#pragma unroll
      for (int m = 0; m < 4; ++m) acc[q][m] = 0.f;
    for (int k = 0; k < CC; k += 4) {
      const float a0 = Wd0[(k + 0) * CC + c], a1 = Wd0[(k + 1) * CC + c];
      const float a2 = Wd0[(k + 2) * CC + c], a3 = Wd0[(k + 3) * CC + c];
      const float b0 = Wd1[(k + 0) * CC + c], b1 = Wd1[(k + 1) * CC + c];
      const float b2 = Wd1[(k + 2) * CC + c], b3 = Wd1[(k + 3) * CC + c];
#pragma unroll
      for (int q = 0; q < 4; ++q) {
        const int nb = p * 4 + q;
        float4 v0 = *(const float4*)&X[nb][0][k];
        acc[q][0] += v0.x * a0 + v0.y * a1 + v0.z * a2 + v0.w * a3;
#pragma unroll
        for (int m = 1; m < 4; ++m) {
          float4 u = *(const float4*)&X[nb][m][k];
          acc[q][m] += u.x * b0 + u.y * b1 + u.z * b2 + u.w * b3;
        }
      }
    }
#pragma unroll
    for (int q = 0; q < 4; ++q)
#pragma unroll
      for (int m = 0; m < 4; ++m) Y[p * 4 + q][m][c] = acc[q][m];
  }
  __syncthreads();
  // ---- stage B: pointwise paths / species product (X := b) ----
#pragma unroll
  for (int q = 0; q < 4; ++q) {
    const int nb = p * 4 + q;
    const float a0 = Y[nb][0][c];
    const float ax = Y[nb][1][c], ay = Y[nb][2][c], az = Y[nb][3][c];
    const float dot = ax * ax + ay * ay + az * az;
    int sidx = 0;
#pragma unroll
    for (int si = 0; si < SS; ++si)
      if (at_s[nb][si] > 0.5f) sidx = si;
    const float a0sq = a0 * a0;
    const float b0v = Wprod0[(sidx * 5 + 0) * CC + c] * a0 +
                      Wprod0[(sidx * 5 + 1) * CC + c] * a0sq +
                      Wprod0[(sidx * 5 + 2) * CC + c] * dot +
                      Wprod0[(sidx * 5 + 3) * CC + c] * (a0sq * a0) +
                      Wprod0[(sidx * 5 + 4) * CC + c] * (a0 * dot);
    const float fac = Wprod1[(sidx * 4 + 0) * CC + c] +
                      Wprod1[(sidx * 4 + 1) * CC + c] * a0 +
                      Wprod1[(sidx * 4 + 2) * CC + c] * a0sq +
                      Wprod1[(sidx * 4 + 3) * CC + c] * dot;
    X[nb][0][c] = b0v;
    X[nb][1][c] = ax * fac;
    X[nb][2][c] = ay * fac;
    X[nb][3][c] = az * fac;
  }
  __syncthreads();
  // ---- stage H: h = b @ [Wp0 | Wp1] (Y := h) ----
  {
    float acc[4][4];
#pragma unroll
    for (int q = 0; q < 4; ++q)
#pragma unroll
      for (int m = 0; m < 4; ++m) acc[q][m] = 0.f;
    for (int k = 0; k < CC; k += 4) {
      const float a0 = Wp0[(k + 0) * CC + c], a1 = Wp0[(k + 1) * CC + c];
      const float a2 = Wp0[(k + 2) * CC + c], a3 = Wp0[(k + 3) * CC + c];
      const float b0 = Wp1[(k + 0) * CC + c], b1 = Wp1[(k + 1) * CC + c];
      const float b2 = Wp1[(k + 2) * CC + c], b3 = Wp1[(k + 3) * CC + c];
#pragma unroll
      for (int q = 0; q < 4; ++q) {
        const int nb = p * 4 + q;
        float4 v0 = *(const float4*)&X[nb][0][k];
        acc[q][0] += v0.x * a0 + v0.y * a1 + v0.z * a2 + v0.w * a3;
#pragma unroll
        for (int m = 1; m < 4; ++m) {
          float4 u = *(const float4*)&X[nb][m][k];
          acc[q][m] += u.x * b0 + u.y * b1 + u.z * b2 + u.w * b3;
        }
      }
    }
#pragma unroll
    for (int q = 0; q < 4; ++q)
#pragma unroll
      for (int m = 0; m < 4; ++m) Y[p * 4 + q][m][c] = acc[q][m];
  }
  __syncthreads();
  // ---- stage F: mh / gate / scalars / vec / nf ----
  if (t < 128) {
    const int nb = t >> 4, m = t & 15;
    float acc = 0.f;
    for (int k = 0; k < CC; ++k) acc += Y[nb][0][k] * Wr1[k * 16 + m];
    mh_s[nb][m] = silu_f(acc);
  }
  __syncthreads();
  if (t < 8) {
    float g = 0.f;
#pragma unroll
    for (int m = 0; m < 16; ++m) g += mh_s[t][m] * Wg[m];
    gate_s[t] = silu_f(g);
  }
#pragma unroll
  for (int q = 0; q < 4; ++q) {
    const int nb = p * 4 + q;
    float acc = 0.f;
#pragma unroll
    for (int m = 0; m < 16; ++m) acc += mh_s[nb][m] * Wr2[m * CC + c];
    out_scalars[(size_t)(n0 + nb) * CC + c] = acc;
  }
  __syncthreads();
  if (t < 24) {
    const int nb = t / 3, i = t % 3;
    float acc = 0.f;
    for (int k = 0; k < CC; ++k) acc += Y[nb][1 + i][k] * wv[k];
    out_vec[(size_t)(n0 + nb) * 3 + i] = acc * gate_s[nb];
  }
  for (int i = t; i < 4096; i += 256) out_nf[(size_t)n0 * 512 + i] = Yf[i];
}

extern "C" void kernel_launch(void* const* d_in, const int* in_sizes, int n_in,
                              void* d_out, int out_size, void* d_ws, size_t ws_size,
                              hipStream_t stream) {
  const float* vectors    = (const float*)d_in[0];
  const float* lengths    = (const float*)d_in[1];
  const float* node_feats = (const float*)d_in[2];
  const float* node_attrs = (const float*)d_in[3];
  const float* edge_feats = (const float*)d_in[4];
  const int*   edge_index = (const int*)d_in[5];
  const float* W_up       = (const float*)d_in[6];
  const float* radial_w1  = (const float*)d_in[7];
  const float* radial_b1  = (const float*)d_in[8];
  const float* radial_w2  = (const float*)d_in[9];
  const float* Wd0        = (const float*)d_in[10];
  const float* Wd1        = (const float*)d_in[11];
  const float* Wprod0     = (const float*)d_in[12];
  const float* Wprod1     = (const float*)d_in[13];
  const float* Wp0        = (const float*)d_in[14];
  const float* Wp1        = (const float*)d_in[15];
  const float* Wr1        = (const float*)d_in[16];
  const float* Wr2        = (const float*)d_in[17];
  const float* Wg         = (const float*)d_in[18];
  const float* wv         = (const float*)d_in[19];

  float* out = (float*)d_out;
  float* out_scalars = out;
  float* out_vec = out + (size_t)NN * CC;
  float* out_nf = out + (size_t)NN * CC + (size_t)NN * 3;
  float* sbuf = out_nf;  // reuse the nf output region (N*512 floats) as s-scratch

  float* hbuf = (float*)d_ws;                      // N*C floats
  int* cnt = (int*)(hbuf + (size_t)NN * CC);       // N ints
  int* offs = cnt + NN;                            // N+1 ints
  int* cur = offs + NN + 1;                        // N ints
  int* ord = cur + NN;                             // E ints

  const int* senders = edge_index;
  const int* receivers = edge_index + NE;

  hipMemsetAsync(cnt, 0, NN * sizeof(int), stream);
  k_node_h<<<NN / 8, 128, 0, stream>>>(node_feats, W_up, hbuf);
  k_hist<<<NE / 256, 256, 0, stream>>>(receivers, cnt);
  k_scan<<<1, 1024, 0, stream>>>(cnt, offs, cur);
  k_fill<<<NE / 256, 256, 0, stream>>>(receivers, cur, ord);
  k_edge<<<2048, 256, 0, stream>>>(vectors, lengths, edge_feats, senders, hbuf,
                                   radial_w1, radial_b1, radial_w2, offs, ord, sbuf);
  k_down<<<NN / 8, 256, 0, stream>>>(sbuf, node_attrs, Wd0, Wd1, Wprod0, Wprod1,
                                     Wp0, Wp1, Wr1, Wr2, Wg, wv,
                                     out_scalars, out_vec, out_nf);
}

// Round 2
// 466.249 us; speedup vs baseline: 1.7856x; 1.7856x over previous
//
#include <hip/hip_runtime.h>

#define NN 20000
#define NE 320000
#define CC 128
#define SS 10

typedef __attribute__((ext_vector_type(8))) short short8;
typedef __attribute__((ext_vector_type(4))) float f32x4;

__device__ __forceinline__ float silu_f(float x) { return x / (1.f + __expf(-x)); }

__device__ __forceinline__ unsigned short f2bf(float x) {  // RNE float->bf16 bits
  unsigned u = __float_as_uint(x);
  unsigned r = u + 0x7FFFu + ((u >> 16) & 1u);
  return (unsigned short)(r >> 16);
}
__device__ __forceinline__ float bf2f(unsigned short h) {
  return __uint_as_float(((unsigned)h) << 16);
}

// ---------------- h = node_feats @ W_up, 8 nodes per 128-thread block ----------------
__global__ __launch_bounds__(128) void k_node_h(const float* __restrict__ nf,
                                                const float* __restrict__ W,
                                                float* __restrict__ h) {
  __shared__ __align__(16) float rows[8][CC];
  const int c = threadIdx.x;
  const int n0 = blockIdx.x * 8;
#pragma unroll
  for (int q = 0; q < 8; ++q) rows[q][c] = nf[(n0 + q) * CC + c];
  __syncthreads();
  float acc[8] = {0.f, 0.f, 0.f, 0.f, 0.f, 0.f, 0.f, 0.f};
  for (int k = 0; k < CC; k += 4) {
    const float w0 = W[(k + 0) * CC + c];
    const float w1 = W[(k + 1) * CC + c];
    const float w2 = W[(k + 2) * CC + c];
    const float w3 = W[(k + 3) * CC + c];
#pragma unroll
    for (int q = 0; q < 8; ++q) {
      float4 v = *(const float4*)&rows[q][k];
      acc[q] += v.x * w0 + v.y * w1 + v.z * w2 + v.w * w3;
    }
  }
#pragma unroll
  for (int q = 0; q < 8; ++q) h[(n0 + q) * CC + c] = acc[q];
}

// ---------------- CSR build: histogram / scan / fill ----------------
__global__ void k_hist(const int* __restrict__ recv, int* __restrict__ cnt) {
  int i = blockIdx.x * blockDim.x + threadIdx.x;
  if (i < NE) atomicAdd(&cnt[recv[i]], 1);
}

__global__ __launch_bounds__(1024) void k_scan(const int* __restrict__ cnt,
                                               int* __restrict__ offs,
                                               int* __restrict__ cur) {
  __shared__ int buf[1024];
  __shared__ int carry_s;
  const int t = threadIdx.x;
  if (t == 0) carry_s = 0;
  __syncthreads();
  for (int base = 0; base < NN; base += 1024) {
    int carry = carry_s;
    int v = (base + t < NN) ? cnt[base + t] : 0;
    int x = v;
    buf[t] = x;
    __syncthreads();
    for (int off = 1; off < 1024; off <<= 1) {
      int y = (t >= off) ? buf[t - off] : 0;
      __syncthreads();
      x += y;
      buf[t] = x;
      __syncthreads();
    }
    if (base + t < NN) {
      offs[base + t] = carry + x - v;
      cur[base + t] = carry + x - v;
    }
    __syncthreads();
    if (t == 1023) carry_s = carry + buf[1023];
    __syncthreads();
  }
  if (t == 0) offs[NN] = carry_s;
}

__global__ void k_fill(const int* __restrict__ recv, int* __restrict__ cur,
                       int* __restrict__ ord) {
  int i = blockIdx.x * blockDim.x + threadIdx.x;
  if (i < NE) {
    int r = recv[i];
    int pos = atomicAdd(&cur[r], 1);
    ord[pos] = i;
  }
}

// ---------------- edge aggregation via MFMA ----------------
// Block = 256 threads = 4 waves, grid-strides over nodes. Per node, edges are
// processed 16 at a time: hid(16x64) computed in LDS, w(16x256) = hid @ W2 via
// bf16x3-split MFMA (W2 hi/lo fragments live in registers for the whole kernel),
// then each lane multiplies its w-fragment by gathered h[sender] and Y1 and
// accumulates s-partials in registers; shfl reduce + write once per node.
// Wave wv owns output cols [wv*64, wv*64+64): waves 0,1 -> w0/s0, waves 2,3 -> w1/s1.
__global__ __launch_bounds__(256, 2) void k_edge_mfma(
    const float* __restrict__ vectors, const float* __restrict__ lengths,
    const float* __restrict__ efeat, const int* __restrict__ senders,
    const float* __restrict__ hbuf, const float* __restrict__ W1,
    const float* __restrict__ B1, const float* __restrict__ W2,
    const int* __restrict__ offs, const int* __restrict__ ord,
    float* __restrict__ sout) {
  __shared__ float W1s[9 * 64];
  __shared__ float B1s[64];
  __shared__ float ed[16][12];
  __shared__ float y1s[16][3];
  __shared__ int snd[16];
  __shared__ __align__(16) float hid[16][68];  // pad 4: rows stay 16B-aligned

  const int t = threadIdx.x;
  const int l = t & 63;
  const int wv = t >> 6;   // wave 0..3
  const int lg = l >> 4;   // lane group 0..3
  const int lm = l & 15;

  for (int i = t; i < 576; i += 256) W1s[i] = W1[i];
  if (t < 64) B1s[t] = B1[t];

  // --- W2 bf16 hi/lo fragments in registers (constant for whole kernel) ---
  // k-index formula MUST match the A-side formula (any shared k-permutation cancels).
  short8 Bhi[2][4], Blo[2][4];
  for (int s = 0; s < 2; ++s) {
    for (int ct = 0; ct < 4; ++ct) {
      short8 bh, bl;
      for (int j = 0; j < 8; ++j) {
        const int k = s * 32 + lg * 8 + j;
        const int col = wv * 64 + ct * 16 + lm;
        const float x = W2[k * 256 + col];
        const unsigned short h = f2bf(x);
        bh[j] = (short)h;
        bl[j] = (short)f2bf(x - bf2f(h));
      }
      Bhi[s][ct] = bh;
      Blo[s][ct] = bl;
    }
  }

  float p0[4] = {0.f, 0.f, 0.f, 0.f};
  float px[4] = {0.f, 0.f, 0.f, 0.f};
  float py[4] = {0.f, 0.f, 0.f, 0.f};
  float pz[4] = {0.f, 0.f, 0.f, 0.f};
  const float inv = 1.f / 16.f;

  for (int n = blockIdx.x; n < NN; n += gridDim.x) {
    const int beg = offs[n], end = offs[n + 1];
    for (int cb = beg; cb < end; cb += 16) {
      int cnt = end - cb;
      if (cnt > 16) cnt = 16;
      __syncthreads();  // protect LDS (ed/snd/hid/y1s) reuse from previous chunk
      if (t < 16) snd[t] = (t < cnt) ? senders[ord[cb + t]] : 0;
      if (t < 192) {
        const int e = t / 12, r = t % 12;
        float v = 0.f;
        if (e < cnt) {
          const int eid = ord[cb + e];
          v = (r < 3) ? vectors[eid * 3 + r]
                      : (r == 3) ? lengths[eid] : efeat[eid * 8 + (r - 4)];
        }
        ed[e][r] = v;
      }
      __syncthreads();
      {  // hid: thread t computes hid[e][kq*4 .. kq*4+3]
        const int e = t & 15, kq = t >> 4;
        const float e3 = ed[e][3];
        const bool live = (e < cnt);
#pragma unroll
        for (int kk = 0; kk < 4; ++kk) {
          const int k = kq * 4 + kk;
          float x = B1s[k];
#pragma unroll
          for (int r = 0; r < 8; ++r) x += ed[e][4 + r] * W1s[r * 64 + k];
          x += e3 * W1s[8 * 64 + k];
          hid[e][k] = live ? silu_f(x) : 0.f;  // padded rows contribute 0
        }
        if (t < 16) {
          const float vx = ed[t][0], vy = ed[t][1], vz = ed[t][2];
          const float nr = sqrtf(vx * vx + vy * vy + vz * vz) + 1e-9f;
          const float sc = 1.7320508075688772f / nr;
          y1s[t][0] = vx * sc;
          y1s[t][1] = vy * sc;
          y1s[t][2] = vz * sc;
        }
      }
      __syncthreads();
      // A fragments (hi/lo split of hid)
      short8 Ahi[2], Alo[2];
#pragma unroll
      for (int s = 0; s < 2; ++s) {
        short8 ah, al;
#pragma unroll
        for (int j = 0; j < 8; ++j) {
          const float x = hid[lm][s * 32 + lg * 8 + j];
          const unsigned short h = f2bf(x);
          ah[j] = (short)h;
          al[j] = (short)f2bf(x - bf2f(h));
        }
        Ahi[s] = ah;
        Alo[s] = al;
      }
      // w tile = hid @ W2 via 3-product bf16 split (lo*lo dropped, ~2^-16 rel)
      f32x4 acc[4];
#pragma unroll
      for (int ct = 0; ct < 4; ++ct) acc[ct] = (f32x4){0.f, 0.f, 0.f, 0.f};
#pragma unroll
      for (int s = 0; s < 2; ++s) {
#pragma unroll
        for (int ct = 0; ct < 4; ++ct) {
          acc[ct] = __builtin_amdgcn_mfma_f32_16x16x32_bf16(Ahi[s], Bhi[s][ct], acc[ct], 0, 0, 0);
          acc[ct] = __builtin_amdgcn_mfma_f32_16x16x32_bf16(Ahi[s], Blo[s][ct], acc[ct], 0, 0, 0);
          acc[ct] = __builtin_amdgcn_mfma_f32_16x16x32_bf16(Alo[s], Bhi[s][ct], acc[ct], 0, 0, 0);
        }
      }
      // consume: C/D layout col=lane&15, row=(lane>>4)*4+reg  [m89/m91-verified]
      const int e0 = lg * 4;
      const int r0 = snd[e0 + 0], r1 = snd[e0 + 1], r2 = snd[e0 + 2], r3 = snd[e0 + 3];
      if (wv < 2) {
#pragma unroll
        for (int ct = 0; ct < 4; ++ct) {
          const int col = wv * 64 + ct * 16 + lm;  // 0..127
          p0[ct] += acc[ct][0] * hbuf[r0 * CC + col] + acc[ct][1] * hbuf[r1 * CC + col] +
                    acc[ct][2] * hbuf[r2 * CC + col] + acc[ct][3] * hbuf[r3 * CC + col];
        }
      } else {
        const float y00 = y1s[e0 + 0][0], y01 = y1s[e0 + 0][1], y02 = y1s[e0 + 0][2];
        const float y10 = y1s[e0 + 1][0], y11 = y1s[e0 + 1][1], y12 = y1s[e0 + 1][2];
        const float y20 = y1s[e0 + 2][0], y21 = y1s[e0 + 2][1], y22 = y1s[e0 + 2][2];
        const float y30 = y1s[e0 + 3][0], y31 = y1s[e0 + 3][1], y32 = y1s[e0 + 3][2];
#pragma unroll
        for (int ct = 0; ct < 4; ++ct) {
          const int col = (wv - 2) * 64 + ct * 16 + lm;  // 0..127 within w1
          const float m0 = acc[ct][0] * hbuf[r0 * CC + col];
          const float m1 = acc[ct][1] * hbuf[r1 * CC + col];
          const float m2 = acc[ct][2] * hbuf[r2 * CC + col];
          const float m3 = acc[ct][3] * hbuf[r3 * CC + col];
          px[ct] += m0 * y00 + m1 * y10 + m2 * y20 + m3 * y30;
          py[ct] += m0 * y01 + m1 * y11 + m2 * y21 + m3 * y31;
          pz[ct] += m0 * y02 + m1 * y12 + m2 * y22 + m3 * y32;
        }
      }
    }  // chunk loop
    // reduce over the 4 lane-groups (lanes l, l^16, l^32, l^48 share a column) + write
    if (wv < 2) {
#pragma unroll
      for (int ct = 0; ct < 4; ++ct) {
        float v = p0[ct];
        v += __shfl_xor(v, 16, 64);
        v += __shfl_xor(v, 32, 64);
        if (lg == 0) sout[(size_t)n * 512 + wv * 64 + ct * 16 + lm] = v * inv;
        p0[ct] = 0.f;
      }
    } else {
#pragma unroll
      for (int ct = 0; ct < 4; ++ct) {
        float vx = px[ct], vy = py[ct], vz = pz[ct];
        vx += __shfl_xor(vx, 16, 64);
        vx += __shfl_xor(vx, 32, 64);
        vy += __shfl_xor(vy, 16, 64);
        vy += __shfl_xor(vy, 32, 64);
        vz += __shfl_xor(vz, 16, 64);
        vz += __shfl_xor(vz, 32, 64);
        if (lg == 0) {
          const int c = (wv - 2) * 64 + ct * 16 + lm;
          sout[(size_t)n * 512 + 128 + c] = vx * inv;
          sout[(size_t)n * 512 + 256 + c] = vy * inv;
          sout[(size_t)n * 512 + 384 + c] = vz * inv;
        }
        px[ct] = 0.f;
        py[ct] = 0.f;
        pz[ct] = 0.f;
      }
    }
  }  // node loop
}

// ---------------- fused downstream: 8 nodes per 256-thread block ----------------
__global__ __launch_bounds__(256) void k_down(
    const float* __restrict__ sbuf, const float* __restrict__ attrs,
    const float* __restrict__ Wd0, const float* __restrict__ Wd1,
    const float* __restrict__ Wprod0, const float* __restrict__ Wprod1,
    const float* __restrict__ Wp0, const float* __restrict__ Wp1,
    const float* __restrict__ Wr1, const float* __restrict__ Wr2,
    const float* __restrict__ Wg, const float* __restrict__ wv,
    float* __restrict__ out_scalars, float* __restrict__ out_vec,
    float* __restrict__ out_nf) {
  __shared__ __align__(16) float X[8][4][CC];  // s, then b
  __shared__ __align__(16) float Y[8][4][CC];  // a, then h
  __shared__ float at_s[8][SS];
  __shared__ float mh_s[8][16];
  __shared__ float gate_s[8];
  const int t = threadIdx.x;
  const int c = t & 127, p = t >> 7;
  const int n0 = blockIdx.x * 8;
  float* Xf = &X[0][0][0];
  float* Yf = &Y[0][0][0];
  for (int i = t; i < 4096; i += 256) Xf[i] = sbuf[(size_t)n0 * 512 + i];
  for (int i = t; i < 8 * SS; i += 256) at_s[i / SS][i % SS] = attrs[n0 * SS + i];
  __syncthreads();
  // ---- stage A: a = s @ [Wd0 | Wd1] ----
  {
    float acc[4][4];
#pragma unroll
    for (int q = 0; q < 4; ++q)
#pragma unroll
      for (int m = 0; m < 4; ++m) acc[q][m] = 0.f;
    for (int k = 0; k < CC; k += 4) {
      const float a0 = Wd0[(k + 0) * CC + c], a1 = Wd0[(k + 1) * CC + c];
      const float a2 = Wd0[(k + 2) * CC + c], a3 = Wd0[(k + 3) * CC + c];
      const float b0 = Wd1[(k + 0) * CC + c], b1 = Wd1[(k + 1) * CC + c];
      const float b2 = Wd1[(k + 2) * CC + c], b3 = Wd1[(k + 3) * CC + c];
#pragma unroll
      for (int q = 0; q < 4; ++q) {
        const int nb = p * 4 + q;
        float4 v0 = *(const float4*)&X[nb][0][k];
        acc[q][0] += v0.x * a0 + v0.y * a1 + v0.z * a2 + v0.w * a3;
#pragma unroll
        for (int m = 1; m < 4; ++m) {
          float4 u = *(const float4*)&X[nb][m][k];
          acc[q][m] += u.x * b0 + u.y * b1 + u.z * b2 + u.w * b3;
        }
      }
    }
#pragma unroll
    for (int q = 0; q < 4; ++q)
#pragma unroll
      for (int m = 0; m < 4; ++m) Y[p * 4 + q][m][c] = acc[q][m];
  }
  __syncthreads();
  // ---- stage B: pointwise paths / species product (X := b) ----
#pragma unroll
  for (int q = 0; q < 4; ++q) {
    const int nb = p * 4 + q;
    const float a0 = Y[nb][0][c];
    const float ax = Y[nb][1][c], ay = Y[nb][2][c], az = Y[nb][3][c];
    const float dot = ax * ax + ay * ay + az * az;
    int sidx = 0;
#pragma unroll
    for (int si = 0; si < SS; ++si)
      if (at_s[nb][si] > 0.5f) sidx = si;
    const float a0sq = a0 * a0;
    const float b0v = Wprod0[(sidx * 5 + 0) * CC + c] * a0 +
                      Wprod0[(sidx * 5 + 1) * CC + c] * a0sq +
                      Wprod0[(sidx * 5 + 2) * CC + c] * dot +
                      Wprod0[(sidx * 5 + 3) * CC + c] * (a0sq * a0) +
                      Wprod0[(sidx * 5 + 4) * CC + c] * (a0 * dot);
    const float fac = Wprod1[(sidx * 4 + 0) * CC + c] +
                      Wprod1[(sidx * 4 + 1) * CC + c] * a0 +
                      Wprod1[(sidx * 4 + 2) * CC + c] * a0sq +
                      Wprod1[(sidx * 4 + 3) * CC + c] * dot;
    X[nb][0][c] = b0v;
    X[nb][1][c] = ax * fac;
    X[nb][2][c] = ay * fac;
    X[nb][3][c] = az * fac;
  }
  __syncthreads();
  // ---- stage H: h = b @ [Wp0 | Wp1] (Y := h) ----
  {
    float acc[4][4];
#pragma unroll
    for (int q = 0; q < 4; ++q)
#pragma unroll
      for (int m = 0; m < 4; ++m) acc[q][m] = 0.f;
    for (int k = 0; k < CC; k += 4) {
      const float a0 = Wp0[(k + 0) * CC + c], a1 = Wp0[(k + 1) * CC + c];
      const float a2 = Wp0[(k + 2) * CC + c], a3 = Wp0[(k + 3) * CC + c];
      const float b0 = Wp1[(k + 0) * CC + c], b1 = Wp1[(k + 1) * CC + c];
      const float b2 = Wp1[(k + 2) * CC + c], b3 = Wp1[(k + 3) * CC + c];
#pragma unroll
      for (int q = 0; q < 4; ++q) {
        const int nb = p * 4 + q;
        float4 v0 = *(const float4*)&X[nb][0][k];
        acc[q][0] += v0.x * a0 + v0.y * a1 + v0.z * a2 + v0.w * a3;
#pragma unroll
        for (int m = 1; m < 4; ++m) {
          float4 u = *(const float4*)&X[nb][m][k];
          acc[q][m] += u.x * b0 + u.y * b1 + u.z * b2 + u.w * b3;
        }
      }
    }
#pragma unroll
    for (int q = 0; q < 4; ++q)
#pragma unroll
      for (int m = 0; m < 4; ++m) Y[p * 4 + q][m][c] = acc[q][m];
  }
  __syncthreads();
  // ---- stage F: mh / gate / scalars / vec / nf ----
  if (t < 128) {
    const int nb = t >> 4, m = t & 15;
    float acc = 0.f;
    for (int k = 0; k < CC; ++k) acc += Y[nb][0][k] * Wr1[k * 16 + m];
    mh_s[nb][m] = silu_f(acc);
  }
  __syncthreads();
  if (t < 8) {
    float g = 0.f;
#pragma unroll
    for (int m = 0; m < 16; ++m) g += mh_s[t][m] * Wg[m];
    gate_s[t] = silu_f(g);
  }
#pragma unroll
  for (int q = 0; q < 4; ++q) {
    const int nb = p * 4 + q;
    float acc = 0.f;
#pragma unroll
    for (int m = 0; m < 16; ++m) acc += mh_s[nb][m] * Wr2[m * CC + c];
    out_scalars[(size_t)(n0 + nb) * CC + c] = acc;
  }
  __syncthreads();
  if (t < 24) {
    const int nb = t / 3, i = t % 3;
    float acc = 0.f;
    for (int k = 0; k < CC; ++k) acc += Y[nb][1 + i][k] * wv[k];
    out_vec[(size_t)(n0 + nb) * 3 + i] = acc * gate_s[nb];
  }
  for (int i = t; i < 4096; i += 256) out_nf[(size_t)n0 * 512 + i] = Yf[i];
}

extern "C" void kernel_launch(void* const* d_in, const int* in_sizes, int n_in,
                              void* d_out, int out_size, void* d_ws, size_t ws_size,
                              hipStream_t stream) {
  const float* vectors    = (const float*)d_in[0];
  const float* lengths    = (const float*)d_in[1];
  const float* node_feats = (const float*)d_in[2];
  const float* node_attrs = (const float*)d_in[3];
  const float* edge_feats = (const float*)d_in[4];
  const int*   edge_index = (const int*)d_in[5];
  const float* W_up       = (const float*)d_in[6];
  const float* radial_w1  = (const float*)d_in[7];
  const float* radial_b1  = (const float*)d_in[8];
  const float* radial_w2  = (const float*)d_in[9];
  const float* Wd0        = (const float*)d_in[10];
  const float* Wd1        = (const float*)d_in[11];
  const float* Wprod0     = (const float*)d_in[12];
  const float* Wprod1     = (const float*)d_in[13];
  const float* Wp0        = (const float*)d_in[14];
  const float* Wp1        = (const float*)d_in[15];
  const float* Wr1        = (const float*)d_in[16];
  const float* Wr2        = (const float*)d_in[17];
  const float* Wg         = (const float*)d_in[18];
  const float* wv         = (const float*)d_in[19];

  float* out = (float*)d_out;
  float* out_scalars = out;
  float* out_vec = out + (size_t)NN * CC;
  float* out_nf = out + (size_t)NN * CC + (size_t)NN * 3;
  float* sbuf = out_nf;  // reuse the nf output region (N*512 floats) as s-scratch

  float* hbuf = (float*)d_ws;                      // N*C floats
  int* cnt = (int*)(hbuf + (size_t)NN * CC);       // N ints
  int* offs = cnt + NN;                            // N+1 ints
  int* cur = offs + NN + 1;                        // N ints
  int* ord = cur + NN;                             // E ints

  const int* senders = edge_index;
  const int* receivers = edge_index + NE;

  hipMemsetAsync(cnt, 0, NN * sizeof(int), stream);
  k_node_h<<<NN / 8, 128, 0, stream>>>(node_feats, W_up, hbuf);
  k_hist<<<NE / 256, 256, 0, stream>>>(receivers, cnt);
  k_scan<<<1, 1024, 0, stream>>>(cnt, offs, cur);
  k_fill<<<NE / 256, 256, 0, stream>>>(receivers, cur, ord);
  k_edge_mfma<<<2048, 256, 0, stream>>>(vectors, lengths, edge_feats, senders, hbuf,
                                        radial_w1, radial_b1, radial_w2, offs, ord, sbuf);
  k_down<<<NN / 8, 256, 0, stream>>>(sbuf, node_attrs, Wd0, Wd1, Wprod0, Wprod1,
                                     Wp0, Wp1, Wr1, Wr2, Wg, wv,
                                     out_scalars, out_vec, out_nf);
}